// Round 8
// baseline (359.620 us; speedup 1.0000x reference)
//
#include <hip/hip_runtime.h>

// Shapes (fixed): B=64, C_IN=512, T=16, C_OUT=512, K=3, E=16
// ws layout (floats):
//   rf     @ 0        : 64*16          = 1024
//   pooled @ 1024     : [c][b] 512*64  = 32768
//   xt     @ 33792    : [i][b][20]     = 512*64*20 = 655360  (floats 0..15 = x[b][i][:], 16..19 pad)
//   part   @ 689152   : [ic][b][o][t]  = 8*64*512*16 = 4194304
// total = 4,883,456 floats = 19.5 MB

#define GLD_LDS16(gp, lp)                                      \
  __builtin_amdgcn_global_load_lds(                            \
      (const __attribute__((address_space(1))) void*)(gp),     \
      (__attribute__((address_space(3))) void*)(lp), 16, 0, 0)

// K1: xt[i][b][0..15] = x[b][i][t] (+4 pad), pooled[c][b] = mean_t x[b][c][t]
__global__ __launch_bounds__(256) void k1_transpose_pool(const float* __restrict__ x,
                                                         float* __restrict__ pooled,
                                                         float* __restrict__ xt) {
  int g = blockIdx.x * 256 + threadIdx.x;  // c = g>>6, b = g&63 (b = lane)
  int c = g >> 6;
  int b = g & 63;
  const float4* xb = (const float4*)(x + ((size_t)b * 512 + c) * 16);
  float4 v0 = xb[0], v1 = xb[1], v2 = xb[2], v3 = xb[3];
  float s = v0.x + v0.y + v0.z + v0.w + v1.x + v1.y + v1.z + v1.w +
            v2.x + v2.y + v2.z + v2.w + v3.x + v3.y + v3.z + v3.w;
  pooled[c * 64 + b] = s * 0.0625f;  // mean over T=16
  float4* row = (float4*)(xt + ((size_t)c * 64 + b) * 20);
  row[0] = v0;
  row[1] = v1;
  row[2] = v2;
  row[3] = v3;
  row[4] = make_float4(0.f, 0.f, 0.f, 0.f);  // pad (staged but never read)
}

// K1b: rf[b][e] = sum_c pooled[b][c]*rf_w[e][c] + rf_b[e]
__global__ __launch_bounds__(256) void k1b_rf(const float* __restrict__ pooled,
                                              const float* __restrict__ rf_w,
                                              const float* __restrict__ rf_b,
                                              float* __restrict__ rf) {
  __shared__ __align__(16) float ps[16 * 520];   // [b_local][c]
  __shared__ __align__(16) float wsm[16 * 520];  // [e][c]
  int tid = threadIdx.x, bg = blockIdx.x;
#pragma unroll
  for (int j = 0; j < 8; ++j) {
    int g = tid + j * 256;  // 0..2047
    int e = g >> 7, q = g & 127;
    *(float4*)&wsm[e * 520 + q * 4] = *(const float4*)&rf_w[e * 512 + q * 4];
  }
#pragma unroll
  for (int j = 0; j < 8; ++j) {
    int g = tid + j * 256;
    int c = g >> 2, q = g & 3;
    float4 v = *(const float4*)&pooled[c * 64 + bg * 16 + q * 4];
    ps[(q * 4 + 0) * 520 + c] = v.x;
    ps[(q * 4 + 1) * 520 + c] = v.y;
    ps[(q * 4 + 2) * 520 + c] = v.z;
    ps[(q * 4 + 3) * 520 + c] = v.w;
  }
  __syncthreads();
  int bl = tid >> 4, e = tid & 15;
  const float4* pr = (const float4*)&ps[bl * 520];
  const float4* wr = (const float4*)&wsm[e * 520];
  float s0 = 0, s1 = 0, s2 = 0, s3 = 0;
#pragma unroll 8
  for (int c4 = 0; c4 < 128; ++c4) {
    float4 p = pr[c4];
    float4 w = wr[c4];
    s0 = fmaf(p.x, w.x, s0);
    s1 = fmaf(p.y, w.y, s1);
    s2 = fmaf(p.z, w.z, s2);
    s3 = fmaf(p.w, w.w, s3);
  }
  rf[(bg * 16 + bl) * 16 + e] = s0 + s1 + s2 + s3 + rf_b[e];
}

// K2: fused synthesis + conv. Block = 256 thr (4 waves), lane = b, wave owns one o.
// Grid (128 ox, 8 ic): o = ox*4 + wave, i-chunk = ic*64, 8 staged subs of 8 i,
// each processed as two halves of 4 i to keep peak register demand low.
__global__ __launch_bounds__(256) void k2_main(const float* __restrict__ weight,
                                               const float* __restrict__ xt,
                                               const float* __restrict__ rf,
                                               float* __restrict__ part) {
  __shared__ __align__(16) float xs[8 * 64 * 20];  // 40 KB -> 4 blocks/CU (LDS-limited)
  const int tid = threadIdx.x;
  const int b = tid & 63;
  const int wv = __builtin_amdgcn_readfirstlane(tid >> 6);  // wave-uniform 0..3
  const int o = blockIdx.x * 4 + wv;
  const int ic = blockIdx.y;

  float rfv[16];
#pragma unroll
  for (int e = 0; e < 16; ++e) rfv[e] = rf[b * 16 + e];
  float acc[16];
#pragma unroll
  for (int t = 0; t < 16; ++t) acc[t] = 0.f;

  const float* wbase = weight + (size_t)o * 1536;  // + e*786432 + i*3 + k

#pragma unroll 1
  for (int sub = 0; sub < 8; ++sub) {
    const int i0 = ic * 64 + sub * 8;
    __syncthreads();  // previous sub's readers done
    // stage 8 i-slices: 2560 f4, direct global->LDS (linear dest = base + lane*16)
    const float* src = xt + (size_t)i0 * 1280;
#pragma unroll
    for (int j = 0; j < 10; ++j) {
      const int idx = (tid + j * 256) * 4;  // float index, 16B-aligned
      GLD_LDS16(src + idx, xs + idx);
    }
    __syncthreads();  // vmcnt(0) drained by compiler before barrier

#pragma unroll
    for (int half = 0; half < 2; ++half) {
      const int i0h = i0 + half * 4;
      // synthesis (e-outer): wsyn[ii][k] = sum_e rfv[e]*W[e,o,i0h+ii,k]; 3x s_load_dwordx4/e
      float wsyn[4][3];
#pragma unroll
      for (int ii = 0; ii < 4; ++ii) {
        wsyn[ii][0] = 0.f;
        wsyn[ii][1] = 0.f;
        wsyn[ii][2] = 0.f;
      }
#pragma unroll
      for (int e = 0; e < 16; ++e) {
        const float4* wp4 = (const float4*)(wbase + (size_t)e * 786432 + (size_t)i0h * 3);
        float4 q0 = wp4[0], q1 = wp4[1], q2 = wp4[2];  // 12 floats = [4 ii][3 k], 48B aligned
        const float r = rfv[e];
        wsyn[0][0] = fmaf(r, q0.x, wsyn[0][0]);
        wsyn[0][1] = fmaf(r, q0.y, wsyn[0][1]);
        wsyn[0][2] = fmaf(r, q0.z, wsyn[0][2]);
        wsyn[1][0] = fmaf(r, q0.w, wsyn[1][0]);
        wsyn[1][1] = fmaf(r, q1.x, wsyn[1][1]);
        wsyn[1][2] = fmaf(r, q1.y, wsyn[1][2]);
        wsyn[2][0] = fmaf(r, q1.z, wsyn[2][0]);
        wsyn[2][1] = fmaf(r, q1.w, wsyn[2][1]);
        wsyn[2][2] = fmaf(r, q2.x, wsyn[2][2]);
        wsyn[3][0] = fmaf(r, q2.y, wsyn[3][0]);
        wsyn[3][1] = fmaf(r, q2.z, wsyn[3][1]);
        wsyn[3][2] = fmaf(r, q2.w, wsyn[3][2]);
      }
      // conv: per ii, 4 aligned b128 LDS reads (row stride 20 floats)
#pragma unroll
      for (int ii = 0; ii < 4; ++ii) {
        const float4* xr4 = (const float4*)(xs + ((half * 4 + ii) * 64 + b) * 20);
        float4 a = xr4[0], c4 = xr4[1], d4 = xr4[2], f4 = xr4[3];
        float xv[16] = {a.x,  a.y,  a.z,  a.w,  c4.x, c4.y, c4.z, c4.w,
                        d4.x, d4.y, d4.z, d4.w, f4.x, f4.y, f4.z, f4.w};
        const float w0 = wsyn[ii][0], w1 = wsyn[ii][1], w2 = wsyn[ii][2];
        // out[t] = w0*x[t-1] + w1*x[t] + w2*x[t+1], zero-padded at edges
        acc[0] = fmaf(w1, xv[0], fmaf(w2, xv[1], acc[0]));
#pragma unroll
        for (int t = 1; t < 15; ++t)
          acc[t] = fmaf(w0, xv[t - 1], fmaf(w1, xv[t], fmaf(w2, xv[t + 1], acc[t])));
        acc[15] = fmaf(w0, xv[14], fmaf(w1, xv[15], acc[15]));
      }
    }
  }

  // partials: part[ic][b][o][t]
  float4* p4 = (float4*)(part + (((size_t)ic * 64 + b) * 512 + o) * 16);
#pragma unroll
  for (int t4 = 0; t4 < 4; ++t4)
    p4[t4] = make_float4(acc[t4 * 4], acc[t4 * 4 + 1], acc[t4 * 4 + 2], acc[t4 * 4 + 3]);
}

// K3: out = sum_ic part + rf@bias + 1
__global__ __launch_bounds__(256) void k3_reduce(const float* __restrict__ part,
                                                 const float* __restrict__ rf,
                                                 const float* __restrict__ bias,
                                                 float* __restrict__ out) {
  int g = blockIdx.x * 256 + threadIdx.x;  // f4 index 0..131071
  int b = g >> 11;
  int o = (g >> 2) & 511;
  float4 s = make_float4(1.f, 1.f, 1.f, 1.f);
#pragma unroll
  for (int ic = 0; ic < 8; ++ic) {
    float4 p = ((const float4*)part)[ic * 131072 + g];
    s.x += p.x;
    s.y += p.y;
    s.z += p.z;
    s.w += p.w;
  }
  int bu = __builtin_amdgcn_readfirstlane(b);  // wave-uniform -> s_load for rf
  float bb = 0.f;
#pragma unroll
  for (int e = 0; e < 16; ++e) bb = fmaf(rf[bu * 16 + e], bias[e * 512 + o], bb);
  s.x += bb;
  s.y += bb;
  s.z += bb;
  s.w += bb;
  ((float4*)out)[g] = s;
}

extern "C" void kernel_launch(void* const* d_in, const int* in_sizes, int n_in,
                              void* d_out, int out_size, void* d_ws, size_t ws_size,
                              hipStream_t stream) {
  const float* x = (const float*)d_in[0];
  const float* rf_w = (const float*)d_in[1];
  const float* rf_b = (const float*)d_in[2];
  const float* weight = (const float*)d_in[3];
  const float* bias = (const float*)d_in[4];
  float* out = (float*)d_out;
  float* ws = (float*)d_ws;

  float* rf = ws;                // 1024
  float* pooled = ws + 1024;     // 32768
  float* xt = ws + 33792;        // 655360
  float* part = ws + 689152;     // 4194304

  k1_transpose_pool<<<128, 256, 0, stream>>>(x, pooled, xt);
  k1b_rf<<<4, 256, 0, stream>>>(pooled, rf_w, rf_b, rf);
  k2_main<<<dim3(128, 8), 256, 0, stream>>>(weight, xt, rf, part);
  k3_reduce<<<512, 256, 0, stream>>>(part, rf, bias, out);
}

// Round 10
// 274.174 us; speedup vs baseline: 1.3117x; 1.3117x over previous
//
#include <hip/hip_runtime.h>

// Shapes (fixed): B=64, C_IN=512, T=16, C_OUT=512, K=3, E=16
// ws layout (floats):
//   rf     @ 0        : 64*16          = 1024
//   pooled @ 1024     : [c][b] 512*64  = 32768
//   xt     @ 33792    : [i][b][20]     = 512*64*20 = 655360  (floats 0..15 = x[b][i][:], 16..19 pad)
//   part   @ 689152   : [ic][b][o][t]  = 8*64*512*16 = 4194304
// total = 4,883,456 floats = 19.5 MB

#define GLD_LDS16(gp, lp)                                      \
  __builtin_amdgcn_global_load_lds(                            \
      (const __attribute__((address_space(1))) void*)(gp),     \
      (__attribute__((address_space(3))) void*)(lp), 16, 0, 0)

// K1: xt[i][b][0..15] = x[b][i][t] (+4 pad), pooled[c][b] = mean_t x[b][c][t]
__global__ __launch_bounds__(256) void k1_transpose_pool(const float* __restrict__ x,
                                                         float* __restrict__ pooled,
                                                         float* __restrict__ xt) {
  int g = blockIdx.x * 256 + threadIdx.x;  // c = g>>6, b = g&63 (b = lane)
  int c = g >> 6;
  int b = g & 63;
  const float4* xb = (const float4*)(x + ((size_t)b * 512 + c) * 16);
  float4 v0 = xb[0], v1 = xb[1], v2 = xb[2], v3 = xb[3];
  float s = v0.x + v0.y + v0.z + v0.w + v1.x + v1.y + v1.z + v1.w +
            v2.x + v2.y + v2.z + v2.w + v3.x + v3.y + v3.z + v3.w;
  pooled[c * 64 + b] = s * 0.0625f;  // mean over T=16
  float4* row = (float4*)(xt + ((size_t)c * 64 + b) * 20);
  row[0] = v0;
  row[1] = v1;
  row[2] = v2;
  row[3] = v3;
  row[4] = make_float4(0.f, 0.f, 0.f, 0.f);  // pad (staged but never read)
}

// K1b: rf[b][e] = sum_c pooled[b][c]*rf_w[e][c] + rf_b[e]
__global__ __launch_bounds__(256) void k1b_rf(const float* __restrict__ pooled,
                                              const float* __restrict__ rf_w,
                                              const float* __restrict__ rf_b,
                                              float* __restrict__ rf) {
  __shared__ __align__(16) float ps[16 * 520];   // [b_local][c]
  __shared__ __align__(16) float wsm[16 * 520];  // [e][c]
  int tid = threadIdx.x, bg = blockIdx.x;
#pragma unroll
  for (int j = 0; j < 8; ++j) {
    int g = tid + j * 256;  // 0..2047
    int e = g >> 7, q = g & 127;
    *(float4*)&wsm[e * 520 + q * 4] = *(const float4*)&rf_w[e * 512 + q * 4];
  }
#pragma unroll
  for (int j = 0; j < 8; ++j) {
    int g = tid + j * 256;
    int c = g >> 2, q = g & 3;
    float4 v = *(const float4*)&pooled[c * 64 + bg * 16 + q * 4];
    ps[(q * 4 + 0) * 520 + c] = v.x;
    ps[(q * 4 + 1) * 520 + c] = v.y;
    ps[(q * 4 + 2) * 520 + c] = v.z;
    ps[(q * 4 + 3) * 520 + c] = v.w;
  }
  __syncthreads();
  int bl = tid >> 4, e = tid & 15;
  const float4* pr = (const float4*)&ps[bl * 520];
  const float4* wr = (const float4*)&wsm[e * 520];
  float s0 = 0, s1 = 0, s2 = 0, s3 = 0;
#pragma unroll 8
  for (int c4 = 0; c4 < 128; ++c4) {
    float4 p = pr[c4];
    float4 w = wr[c4];
    s0 = fmaf(p.x, w.x, s0);
    s1 = fmaf(p.y, w.y, s1);
    s2 = fmaf(p.z, w.z, s2);
    s3 = fmaf(p.w, w.w, s3);
  }
  rf[(bg * 16 + bl) * 16 + e] = s0 + s1 + s2 + s3 + rf_b[e];
}

// K2: fused synthesis + conv. Block = 256 thr (4 waves), lane = b, wave owns one o.
// Grid (128 ox, 8 ic): o = ox*4 + wave, i-chunk = ic*64, 8 staged subs of 8 i,
// each processed as two halves of 4 i to keep peak register demand low.
// launch_bounds(256, 2): empirical VGPR cap ~= 256/w -> 128, the occupancy
// sweet spot (4 waves/SIMD; R8's 132 VGPRs fell to the 2-waves/SIMD quantum).
__global__ __launch_bounds__(256, 2) void k2_main(const float* __restrict__ weight,
                                                  const float* __restrict__ xt,
                                                  const float* __restrict__ rf,
                                                  float* __restrict__ part) {
  __shared__ __align__(16) float xs[8 * 64 * 20];  // 40 KB -> 4 blocks/CU (LDS-limited)
  const int tid = threadIdx.x;
  const int b = tid & 63;
  const int wv = __builtin_amdgcn_readfirstlane(tid >> 6);  // wave-uniform 0..3
  const int o = blockIdx.x * 4 + wv;
  const int ic = blockIdx.y;

  float rfv[16];
#pragma unroll
  for (int e = 0; e < 16; ++e) rfv[e] = rf[b * 16 + e];
  float acc[16];
#pragma unroll
  for (int t = 0; t < 16; ++t) acc[t] = 0.f;

  const float* wbase = weight + (size_t)o * 1536;  // + e*786432 + i*3 + k

#pragma unroll 1
  for (int sub = 0; sub < 8; ++sub) {
    const int i0 = ic * 64 + sub * 8;
    __syncthreads();  // previous sub's readers done
    // stage 8 i-slices: 2560 f4, direct global->LDS (linear dest = base + lane*16)
    const float* src = xt + (size_t)i0 * 1280;
#pragma unroll
    for (int j = 0; j < 10; ++j) {
      const int idx = (tid + j * 256) * 4;  // float index, 16B-aligned
      GLD_LDS16(src + idx, xs + idx);
    }
    __syncthreads();  // vmcnt(0) drained by compiler before barrier

#pragma unroll
    for (int half = 0; half < 2; ++half) {
      const int i0h = i0 + half * 4;
      // synthesis (e-outer): wsyn[ii][k] = sum_e rfv[e]*W[e,o,i0h+ii,k]; 3x s_load_dwordx4/e
      float wsyn[4][3];
#pragma unroll
      for (int ii = 0; ii < 4; ++ii) {
        wsyn[ii][0] = 0.f;
        wsyn[ii][1] = 0.f;
        wsyn[ii][2] = 0.f;
      }
#pragma unroll
      for (int e = 0; e < 16; ++e) {
        const float4* wp4 = (const float4*)(wbase + (size_t)e * 786432 + (size_t)i0h * 3);
        float4 q0 = wp4[0], q1 = wp4[1], q2 = wp4[2];  // 12 floats = [4 ii][3 k], 48B aligned
        const float r = rfv[e];
        wsyn[0][0] = fmaf(r, q0.x, wsyn[0][0]);
        wsyn[0][1] = fmaf(r, q0.y, wsyn[0][1]);
        wsyn[0][2] = fmaf(r, q0.z, wsyn[0][2]);
        wsyn[1][0] = fmaf(r, q0.w, wsyn[1][0]);
        wsyn[1][1] = fmaf(r, q1.x, wsyn[1][1]);
        wsyn[1][2] = fmaf(r, q1.y, wsyn[1][2]);
        wsyn[2][0] = fmaf(r, q1.z, wsyn[2][0]);
        wsyn[2][1] = fmaf(r, q1.w, wsyn[2][1]);
        wsyn[2][2] = fmaf(r, q2.x, wsyn[2][2]);
        wsyn[3][0] = fmaf(r, q2.y, wsyn[3][0]);
        wsyn[3][1] = fmaf(r, q2.z, wsyn[3][1]);
        wsyn[3][2] = fmaf(r, q2.w, wsyn[3][2]);
      }
      // conv: per ii, 4 aligned b128 LDS reads (row stride 20 floats)
#pragma unroll
      for (int ii = 0; ii < 4; ++ii) {
        const float4* xr4 = (const float4*)(xs + ((half * 4 + ii) * 64 + b) * 20);
        float4 a = xr4[0], c4 = xr4[1], d4 = xr4[2], f4 = xr4[3];
        float xv[16] = {a.x,  a.y,  a.z,  a.w,  c4.x, c4.y, c4.z, c4.w,
                        d4.x, d4.y, d4.z, d4.w, f4.x, f4.y, f4.z, f4.w};
        const float w0 = wsyn[ii][0], w1 = wsyn[ii][1], w2 = wsyn[ii][2];
        // out[t] = w0*x[t-1] + w1*x[t] + w2*x[t+1], zero-padded at edges
        acc[0] = fmaf(w1, xv[0], fmaf(w2, xv[1], acc[0]));
#pragma unroll
        for (int t = 1; t < 15; ++t)
          acc[t] = fmaf(w0, xv[t - 1], fmaf(w1, xv[t], fmaf(w2, xv[t + 1], acc[t])));
        acc[15] = fmaf(w0, xv[14], fmaf(w1, xv[15], acc[15]));
      }
    }
  }

  // partials: part[ic][b][o][t]
  float4* p4 = (float4*)(part + (((size_t)ic * 64 + b) * 512 + o) * 16);
#pragma unroll
  for (int t4 = 0; t4 < 4; ++t4)
    p4[t4] = make_float4(acc[t4 * 4], acc[t4 * 4 + 1], acc[t4 * 4 + 2], acc[t4 * 4 + 3]);
}

// K3: out = sum_ic part + rf@bias + 1
__global__ __launch_bounds__(256) void k3_reduce(const float* __restrict__ part,
                                                 const float* __restrict__ rf,
                                                 const float* __restrict__ bias,
                                                 float* __restrict__ out) {
  int g = blockIdx.x * 256 + threadIdx.x;  // f4 index 0..131071
  int b = g >> 11;
  int o = (g >> 2) & 511;
  float4 s = make_float4(1.f, 1.f, 1.f, 1.f);
#pragma unroll
  for (int ic = 0; ic < 8; ++ic) {
    float4 p = ((const float4*)part)[ic * 131072 + g];
    s.x += p.x;
    s.y += p.y;
    s.z += p.z;
    s.w += p.w;
  }
  int bu = __builtin_amdgcn_readfirstlane(b);  // wave-uniform -> s_load for rf
  float bb = 0.f;
#pragma unroll
  for (int e = 0; e < 16; ++e) bb = fmaf(rf[bu * 16 + e], bias[e * 512 + o], bb);
  s.x += bb;
  s.y += bb;
  s.z += bb;
  s.w += bb;
  ((float4*)out)[g] = s;
}

extern "C" void kernel_launch(void* const* d_in, const int* in_sizes, int n_in,
                              void* d_out, int out_size, void* d_ws, size_t ws_size,
                              hipStream_t stream) {
  const float* x = (const float*)d_in[0];
  const float* rf_w = (const float*)d_in[1];
  const float* rf_b = (const float*)d_in[2];
  const float* weight = (const float*)d_in[3];
  const float* bias = (const float*)d_in[4];
  float* out = (float*)d_out;
  float* ws = (float*)d_ws;

  float* rf = ws;                // 1024
  float* pooled = ws + 1024;     // 32768
  float* xt = ws + 33792;        // 655360
  float* part = ws + 689152;     // 4194304

  k1_transpose_pool<<<128, 256, 0, stream>>>(x, pooled, xt);
  k1b_rf<<<4, 256, 0, stream>>>(pooled, rf_w, rf_b, rf);
  k2_main<<<dim3(128, 8), 256, 0, stream>>>(weight, xt, rf, part);
  k3_reduce<<<512, 256, 0, stream>>>(part, rf, bias, out);
}

// Round 11
// 252.566 us; speedup vs baseline: 1.4239x; 1.0856x over previous
//
#include <hip/hip_runtime.h>

// Shapes (fixed): B=64, C_IN=512, T=16, C_OUT=512, K=3, E=16
// ws layout (floats):
//   rf     @ 0        : 64*16          = 1024
//   pooled @ 1024     : [c][b] 512*64  = 32768
//   xt     @ 33792    : [i][b][20]     = 512*64*20 = 655360  (floats 0..15 = x[b][i][:], 16..19 pad)
//   part   @ 689152   : [ic][b][o][t]  = 8*64*512*16 = 4194304
// total = 4,883,456 floats = 19.5 MB

#define GLD_LDS16(gp, lp)                                      \
  __builtin_amdgcn_global_load_lds(                            \
      (const __attribute__((address_space(1))) void*)(gp),     \
      (__attribute__((address_space(3))) void*)(lp), 16, 0, 0)

// K1: xt[i][b][0..15] = x[b][i][t] (+4 pad), pooled[c][b] = mean_t x[b][c][t]
__global__ __launch_bounds__(256) void k1_transpose_pool(const float* __restrict__ x,
                                                         float* __restrict__ pooled,
                                                         float* __restrict__ xt) {
  int g = blockIdx.x * 256 + threadIdx.x;  // c = g>>6, b = g&63 (b = lane)
  int c = g >> 6;
  int b = g & 63;
  const float4* xb = (const float4*)(x + ((size_t)b * 512 + c) * 16);
  float4 v0 = xb[0], v1 = xb[1], v2 = xb[2], v3 = xb[3];
  float s = v0.x + v0.y + v0.z + v0.w + v1.x + v1.y + v1.z + v1.w +
            v2.x + v2.y + v2.z + v2.w + v3.x + v3.y + v3.z + v3.w;
  pooled[c * 64 + b] = s * 0.0625f;  // mean over T=16
  float4* row = (float4*)(xt + ((size_t)c * 64 + b) * 20);
  row[0] = v0;
  row[1] = v1;
  row[2] = v2;
  row[3] = v3;
  row[4] = make_float4(0.f, 0.f, 0.f, 0.f);  // pad (staged but never read)
}

// K1b: rf[b][e] = sum_c pooled[b][c]*rf_w[e][c] + rf_b[e]
__global__ __launch_bounds__(256) void k1b_rf(const float* __restrict__ pooled,
                                              const float* __restrict__ rf_w,
                                              const float* __restrict__ rf_b,
                                              float* __restrict__ rf) {
  __shared__ __align__(16) float ps[16 * 520];   // [b_local][c]
  __shared__ __align__(16) float wsm[16 * 520];  // [e][c]
  int tid = threadIdx.x, bg = blockIdx.x;
#pragma unroll
  for (int j = 0; j < 8; ++j) {
    int g = tid + j * 256;  // 0..2047
    int e = g >> 7, q = g & 127;
    *(float4*)&wsm[e * 520 + q * 4] = *(const float4*)&rf_w[e * 512 + q * 4];
  }
#pragma unroll
  for (int j = 0; j < 8; ++j) {
    int g = tid + j * 256;
    int c = g >> 2, q = g & 3;
    float4 v = *(const float4*)&pooled[c * 64 + bg * 16 + q * 4];
    ps[(q * 4 + 0) * 520 + c] = v.x;
    ps[(q * 4 + 1) * 520 + c] = v.y;
    ps[(q * 4 + 2) * 520 + c] = v.z;
    ps[(q * 4 + 3) * 520 + c] = v.w;
  }
  __syncthreads();
  int bl = tid >> 4, e = tid & 15;
  const float4* pr = (const float4*)&ps[bl * 520];
  const float4* wr = (const float4*)&wsm[e * 520];
  float s0 = 0, s1 = 0, s2 = 0, s3 = 0;
#pragma unroll 8
  for (int c4 = 0; c4 < 128; ++c4) {
    float4 p = pr[c4];
    float4 w = wr[c4];
    s0 = fmaf(p.x, w.x, s0);
    s1 = fmaf(p.y, w.y, s1);
    s2 = fmaf(p.z, w.z, s2);
    s3 = fmaf(p.w, w.w, s3);
  }
  rf[(bg * 16 + bl) * 16 + e] = s0 + s1 + s2 + s3 + rf_b[e];
}

// K2: fused synthesis + conv. Block = 256 thr (4 waves), lane = b, wave owns one o.
// Grid (128 ox, 8 ic): o = ox*4 + wave, i-chunk = ic*64, 8 staged subs of 8 i,
// each processed as two halves of 4 i.
// launch_bounds(256,2) -> VGPR cap 128 = 4 waves/SIMD quantum (R10: VGPR=128, no spill).
// Weight loads go through the VECTOR pipe (wave-uniform global_load_dwordx4, opaque
// vz VGPR defeats uniformity re-scalarization): deep vmcnt queue instead of the
// SGPR-bound s_load train that left R10 at VALUBusy 16% / 205 us.
__global__ __launch_bounds__(256, 2) void k2_main(const float* __restrict__ weight,
                                                  const float* __restrict__ xt,
                                                  const float* __restrict__ rf,
                                                  float* __restrict__ part) {
  __shared__ __align__(16) float xs[8 * 64 * 20];  // 40 KB -> 4 blocks/CU (LDS-limited)
  const int tid = threadIdx.x;
  const int b = tid & 63;
  const int wv = __builtin_amdgcn_readfirstlane(tid >> 6);  // wave-uniform 0..3
  const int o = blockIdx.x * 4 + wv;
  const int ic = blockIdx.y;

  int vz = 0;
  asm volatile("" : "+v"(vz));  // opaque zero in a VGPR -> forces VMEM path for weight

  float rfv[16];
#pragma unroll
  for (int e = 0; e < 16; ++e) rfv[e] = rf[b * 16 + e];
  float acc[16];
#pragma unroll
  for (int t = 0; t < 16; ++t) acc[t] = 0.f;

  const float* wbase = weight + (size_t)o * 1536 + vz;  // + e*786432 + i*3 + k

#pragma unroll 1
  for (int sub = 0; sub < 8; ++sub) {
    const int i0 = ic * 64 + sub * 8;
    __syncthreads();  // previous sub's readers done
    // stage 8 i-slices: 2560 f4, direct global->LDS (linear dest = base + lane*16)
    const float* src = xt + (size_t)i0 * 1280;
#pragma unroll
    for (int j = 0; j < 10; ++j) {
      const int idx = (tid + j * 256) * 4;  // float index, 16B-aligned
      GLD_LDS16(src + idx, xs + idx);
    }
    __syncthreads();  // vmcnt(0) drained by compiler before barrier

#pragma unroll
    for (int half = 0; half < 2; ++half) {
      const int i0h = i0 + half * 4;
      // synthesis (e-outer): wsyn[ii][k] = sum_e rfv[e]*W[e,o,i0h+ii,k]
      // 3x wave-uniform global_load_dwordx4 per e (broadcast; dedup'd in L2)
      float wsyn[4][3];
#pragma unroll
      for (int ii = 0; ii < 4; ++ii) {
        wsyn[ii][0] = 0.f;
        wsyn[ii][1] = 0.f;
        wsyn[ii][2] = 0.f;
      }
#pragma unroll
      for (int e = 0; e < 16; ++e) {
        const float4* wp4 = (const float4*)(wbase + (size_t)e * 786432 + (size_t)i0h * 3);
        float4 q0 = wp4[0], q1 = wp4[1], q2 = wp4[2];  // 12 floats = [4 ii][3 k], 48B aligned
        const float r = rfv[e];
        wsyn[0][0] = fmaf(r, q0.x, wsyn[0][0]);
        wsyn[0][1] = fmaf(r, q0.y, wsyn[0][1]);
        wsyn[0][2] = fmaf(r, q0.z, wsyn[0][2]);
        wsyn[1][0] = fmaf(r, q0.w, wsyn[1][0]);
        wsyn[1][1] = fmaf(r, q1.x, wsyn[1][1]);
        wsyn[1][2] = fmaf(r, q1.y, wsyn[1][2]);
        wsyn[2][0] = fmaf(r, q1.z, wsyn[2][0]);
        wsyn[2][1] = fmaf(r, q1.w, wsyn[2][1]);
        wsyn[2][2] = fmaf(r, q2.x, wsyn[2][2]);
        wsyn[3][0] = fmaf(r, q2.y, wsyn[3][0]);
        wsyn[3][1] = fmaf(r, q2.z, wsyn[3][1]);
        wsyn[3][2] = fmaf(r, q2.w, wsyn[3][2]);
      }
      // conv: per ii, 4 aligned b128 LDS reads (row stride 20 floats)
#pragma unroll
      for (int ii = 0; ii < 4; ++ii) {
        const float4* xr4 = (const float4*)(xs + ((half * 4 + ii) * 64 + b) * 20);
        float4 a = xr4[0], c4 = xr4[1], d4 = xr4[2], f4 = xr4[3];
        float xv[16] = {a.x,  a.y,  a.z,  a.w,  c4.x, c4.y, c4.z, c4.w,
                        d4.x, d4.y, d4.z, d4.w, f4.x, f4.y, f4.z, f4.w};
        const float w0 = wsyn[ii][0], w1 = wsyn[ii][1], w2 = wsyn[ii][2];
        // out[t] = w0*x[t-1] + w1*x[t] + w2*x[t+1], zero-padded at edges
        acc[0] = fmaf(w1, xv[0], fmaf(w2, xv[1], acc[0]));
#pragma unroll
        for (int t = 1; t < 15; ++t)
          acc[t] = fmaf(w0, xv[t - 1], fmaf(w1, xv[t], fmaf(w2, xv[t + 1], acc[t])));
        acc[15] = fmaf(w0, xv[14], fmaf(w1, xv[15], acc[15]));
      }
    }
  }

  // partials: part[ic][b][o][t]
  float4* p4 = (float4*)(part + (((size_t)ic * 64 + b) * 512 + o) * 16);
#pragma unroll
  for (int t4 = 0; t4 < 4; ++t4)
    p4[t4] = make_float4(acc[t4 * 4], acc[t4 * 4 + 1], acc[t4 * 4 + 2], acc[t4 * 4 + 3]);
}

// K3: out = sum_ic part + rf@bias + 1
__global__ __launch_bounds__(256) void k3_reduce(const float* __restrict__ part,
                                                 const float* __restrict__ rf,
                                                 const float* __restrict__ bias,
                                                 float* __restrict__ out) {
  int g = blockIdx.x * 256 + threadIdx.x;  // f4 index 0..131071
  int b = g >> 11;
  int o = (g >> 2) & 511;
  float4 s = make_float4(1.f, 1.f, 1.f, 1.f);
#pragma unroll
  for (int ic = 0; ic < 8; ++ic) {
    float4 p = ((const float4*)part)[ic * 131072 + g];
    s.x += p.x;
    s.y += p.y;
    s.z += p.z;
    s.w += p.w;
  }
  int bu = __builtin_amdgcn_readfirstlane(b);  // wave-uniform -> s_load for rf
  float bb = 0.f;
#pragma unroll
  for (int e = 0; e < 16; ++e) bb = fmaf(rf[bu * 16 + e], bias[e * 512 + o], bb);
  s.x += bb;
  s.y += bb;
  s.z += bb;
  s.w += bb;
  ((float4*)out)[g] = s;
}

extern "C" void kernel_launch(void* const* d_in, const int* in_sizes, int n_in,
                              void* d_out, int out_size, void* d_ws, size_t ws_size,
                              hipStream_t stream) {
  const float* x = (const float*)d_in[0];
  const float* rf_w = (const float*)d_in[1];
  const float* rf_b = (const float*)d_in[2];
  const float* weight = (const float*)d_in[3];
  const float* bias = (const float*)d_in[4];
  float* out = (float*)d_out;
  float* ws = (float*)d_ws;

  float* rf = ws;                // 1024
  float* pooled = ws + 1024;     // 32768
  float* xt = ws + 33792;        // 655360
  float* part = ws + 689152;     // 4194304

  k1_transpose_pool<<<128, 256, 0, stream>>>(x, pooled, xt);
  k1b_rf<<<4, 256, 0, stream>>>(pooled, rf_w, rf_b, rf);
  k2_main<<<dim3(128, 8), 256, 0, stream>>>(weight, xt, rf, part);
  k3_reduce<<<512, 256, 0, stream>>>(part, rf, bias, out);
}